// Round 9
// baseline (287.947 us; speedup 1.0000x reference)
//
#include <hip/hip_runtime.h>

// GMMNet: B=4,S=8,C=3,H=W=384,K=5. Pointwise per pixel; scan over S carries
// per-pixel state (pi[5], mu[15], rinv[5]=1/sigma) in registers.
//
// Round 9: eliminate the 2x v_mov splat per weight-FMA. R8 audit: 2925 VALU
// instrs/wave-step vs ~1250 ideal — compiler materializes vsplat(sgpr) as a
// VGPR pair instead of using VOP3P op_sel broadcast. Fix: weights loaded as
// 64-bit SGPR pairs (s_load_dwordx2, uniform pointer) and fed straight into
// inline-asm v_pk_fma_f32:
//   lo broadcast: op_sel_hi:[0,1,1]        (both halves read src0 low dword)
//   hi broadcast: op_sel:[1,0,0] op_sel_hi:[1,1,1]
// 1 instr/weight, weight never touches a VGPR. Layout re-padded so every
// row/segment starts at an even float offset (pairs never straddle segments).
// Anti-hoist opaque scalar offset retained (R2: hoist->188 VGPR; R3: spill).

namespace {

constexpr int Kk = 5;
constexpr int Cc = 3;
constexpr int CKc = 15;   // C*K
constexpr int Bb = 4;
constexpr int Ss = 8;
constexpr int HWc = 384 * 384;
constexpr int HW2 = HWc / 2;          // pixel-pairs per image
constexpr int BLOCK = 128;

// Contiguous padded weight layout (float offsets). All bases & segment
// starts EVEN so 8-byte pair loads are naturally indexed.
// mu_w1/sg_w1 rows (23 cols) split as [x:3 pad1][mu:15 pad1][rho:5 pad1] = 24.
constexpr int OPB1 = 0;     // pi_b1  5 (pad 6)
constexpr int OPW1 = 6;     // pi_w1  5 rows x pitch 12  ([pi:5 pad1][alpha:5 pad1])
constexpr int OPB2 = 66;    // pi_b2  5 (pad 6)
constexpr int OPW2 = 72;    // pi_w2  5 rows x pitch 6
constexpr int OMB1 = 102;   // mu_b1  15 (pad 16)
constexpr int OMW1 = 118;   // mu_w1  15 rows x pitch 24
constexpr int OMB2 = 478;   // mu_b2  15 (pad 16)
constexpr int OMW2 = 494;   // mu_w2  15 rows x pitch 16
constexpr int OSB1 = 734;   // sg_b1  5 (pad 6)
constexpr int OSW1 = 740;   // sg_w1  5 rows x pitch 24
constexpr int OSB2 = 860;   // sg_b2  5 (pad 6)
constexpr int OSW2 = 866;   // sg_w2  5 rows x pitch 6
constexpr int OGB1 = 896;   // ga_b1  5 (pad 6)
constexpr int OGW1 = 902;   // ga_w1  5 rows x pitch 6
constexpr int OGW2 = 932;   // ga_w2  5 (pad 6)
constexpr int OGB2 = 938;   // ga_b2  1
constexpr int WTOT = 940;   // 3760 B

typedef float v2f __attribute__((ext_vector_type(2)));
typedef unsigned long long wpair;

__device__ __forceinline__ float rcpf(float x) { return __builtin_amdgcn_rcpf(x); }
__device__ __forceinline__ float ex2(float x) { return __builtin_amdgcn_exp2f(x); }

__device__ __forceinline__ v2f vsplat(float w) { v2f r = {w, w}; return r; }
__device__ __forceinline__ v2f vfma(v2f a, v2f b, v2f c) { return __builtin_elementwise_fma(a, b, c); }
__device__ __forceinline__ v2f vexp2(v2f v) { v2f r; r.x = ex2(v.x); r.y = ex2(v.y); return r; }
__device__ __forceinline__ v2f vrcp(v2f v) { v2f r; r.x = rcpf(v.x); r.y = rcpf(v.y); return r; }
__device__ __forceinline__ v2f vmax(v2f a, v2f b) { return __builtin_elementwise_max(a, b); }
__device__ __forceinline__ v2f vrelu(v2f a) { return vmax(a, vsplat(0.0f)); }
constexpr float LOG2E = 1.4426950408889634f;
__device__ __forceinline__ v2f vsigm(v2f a) { return vrcp(vsplat(1.0f) + vexp2(vsplat(-LOG2E) * a)); }

// 8B weight-pair load from an even float index (4B-aligned is fine for SMEM).
__device__ __forceinline__ wpair ldpair(const float* p) {
    wpair w; __builtin_memcpy(&w, p, 8); return w;
}
// a += w.lo * x   (both halves of src0 read the LOW dword of the SGPR pair)
__device__ __forceinline__ void fma_lo(v2f& a, wpair w, v2f x) {
    asm("v_pk_fma_f32 %0, %1, %2, %0 op_sel:[0,0,0] op_sel_hi:[0,1,1]"
        : "+v"(a) : "s"(w), "v"(x));
}
// a += w.hi * x   (both halves of src0 read the HIGH dword of the SGPR pair)
__device__ __forceinline__ void fma_hi(v2f& a, wpair w, v2f x) {
    asm("v_pk_fma_f32 %0, %1, %2, %0 op_sel:[1,0,0] op_sel_hi:[1,1,1]"
        : "+v"(a) : "s"(w), "v"(x));
}
// Dot a row-segment of N weights (even base, padded) against in[0..N).
template <int N>
__device__ __forceinline__ void dotseg(v2f& a, const float* Wrow, const v2f* in) {
#pragma unroll
    for (int p = 0; p < N / 2; p++) {
        wpair w = ldpair(Wrow + 2 * p);
        fma_lo(a, w, in[2 * p]);
        fma_hi(a, w, in[2 * p + 1]);
    }
    if (N & 1) {
        wpair w = ldpair(Wrow + (N - 1));
        fma_lo(a, w, in[N - 1]);
    }
}

__global__ __launch_bounds__(256) void stage_ws_kernel(
    const float* __restrict__ pw1, const float* __restrict__ pb1,
    const float* __restrict__ pw2, const float* __restrict__ pb2,
    const float* __restrict__ mw1, const float* __restrict__ mb1,
    const float* __restrict__ mw2, const float* __restrict__ mb2,
    const float* __restrict__ sw1, const float* __restrict__ sb1,
    const float* __restrict__ sw2, const float* __restrict__ sb2,
    const float* __restrict__ gw1, const float* __restrict__ gb1,
    const float* __restrict__ gw2, const float* __restrict__ gb2,
    float* __restrict__ ws)
{
    const int t = threadIdx.x;
    for (int i = t; i < WTOT; i += 256) ws[i] = 0.0f;   // zero pads (d_ws poisoned)
    __syncthreads();
    auto cp = [&](const float* src, int off, int n) {
        for (int i = t; i < n; i += 256) ws[off + i] = src[i];
    };
    // remap for 23-col rows: [0,3)->+0, [3,18)->+1, [18,23)->+2
    auto cp23 = [&](const float* src, int off, int rows) {
        for (int i = t; i < rows * 23; i += 256) {
            int j = i / 23, c = i - j * 23;
            int dc = (c < 3) ? c : ((c < 18) ? c + 1 : c + 2);
            ws[off + j * 24 + dc] = src[i];
        }
    };
    cp(pb1, OPB1, 5);
    for (int i = t; i < 50; i += 256) {            // pi_w1 5x10 -> pitch 12
        int j = i / 10, c = i - j * 10;
        int dc = (c < 5) ? c : c + 1;
        ws[OPW1 + j * 12 + dc] = pw1[i];
    }
    cp(pb2, OPB2, 5);
    for (int i = t; i < 25; i += 256) {            // pi_w2 5x5 -> pitch 6
        int j = i / 5, c = i - j * 5;
        ws[OPW2 + j * 6 + c] = pw2[i];
    }
    cp(mb1, OMB1, 15);
    cp23(mw1, OMW1, 15);
    cp(mb2, OMB2, 15);
    for (int i = t; i < 225; i += 256) {           // mu_w2 15x15 -> pitch 16
        int j = i / 15, c = i - j * 15;
        ws[OMW2 + j * 16 + c] = mw2[i];
    }
    cp(sb1, OSB1, 5);
    cp23(sw1, OSW1, 5);
    cp(sb2, OSB2, 5);
    for (int i = t; i < 25; i += 256) {            // sg_w2 5x5 -> pitch 6
        int j = i / 5, c = i - j * 5;
        ws[OSW2 + j * 6 + c] = sw2[i];
    }
    cp(gb1, OGB1, 5);
    for (int i = t; i < 25; i += 256) {            // ga_w1 5x5 -> pitch 6
        int j = i / 5, c = i - j * 5;
        ws[OGW1 + j * 6 + c] = gw1[i];
    }
    cp(gw2, OGW2, 5);
    cp(gb2, OGB2, 1);
}

__global__ __launch_bounds__(BLOCK) void gmm_seq_kernel(
    const float* __restrict__ frames,
    const float* __restrict__ mu0,
    const float* __restrict__ Wt,     // contiguous padded weights in d_ws
    float* __restrict__ out)
{
    const int t2 = blockIdx.x * BLOCK + threadIdx.x;   // one thread = 2 adjacent px
    const int b   = t2 / HW2;
    const int rem = t2 - b * HW2;

    const float C0 = 0.06349363593424097f;      // (2*pi)^{-3/2}
    const float NH_L2E = -0.7213475204444817f;  // -0.5 * log2(e)

    // Per-pixel-pair carried state.
    v2f pi[Kk], mu[CKc], rinv[Kk];              // rinv = 1/sigma
#pragma unroll
    for (int k = 0; k < Kk; k++) { pi[k] = vsplat(0.2f); rinv[k] = vsplat(1.0f); }
    {
        const float* mp = mu0 + (size_t)b * CKc * HWc;
#pragma unroll
        for (int j = 0; j < CKc; j++)
            mu[j] = reinterpret_cast<const v2f*>(mp + (size_t)j * HWc)[rem];
    }

    const float* fbase = frames + ((size_t)b * Ss * Cc) * HWc;
    v2f x[Cc];
#pragma unroll
    for (int c = 0; c < Cc; c++)
        x[c] = reinterpret_cast<const v2f*>(fbase + (size_t)c * HWc)[rem];

#pragma unroll 1
    for (int s = 0; s < Ss; s++) {
        // Opaque per-iteration SCALAR offset: value is always 0 but unprovable.
        // Addresses stay wave-uniform (s_load path), loads stay loop-variant.
        long woff = 0;
        asm volatile("" : "+s"(woff));
        const float* W = Wt + woff;

        // Prefetch next frame's pixels (clamped index -> branchless).
        const int sn = (s + 1 < Ss) ? s + 1 : s;
        v2f xn[Cc];
        {
            const float* fp = fbase + ((size_t)sn * Cc) * HWc;
#pragma unroll
            for (int c = 0; c < Cc; c++)
                xn[c] = reinterpret_cast<const v2f*>(fp + (size_t)c * HWc)[rem];
        }

        // ---- density(x; mu, 1/rinv) ----
        v2f alpha[Kk], rho[Kk];
#pragma unroll
        for (int k = 0; k < Kk; k++) {
            v2f inv_s2 = rinv[k] * rinv[k];
            v2f d0 = x[0] - mu[k * Cc + 0];
            v2f d1 = x[1] - mu[k * Cc + 1];
            v2f d2 = x[2] - mu[k * Cc + 2];
            v2f dist = vfma(d0, d0, vfma(d1, d1, d2 * d2));
            v2f coef = vsplat(C0) * inv_s2 * rinv[k];      // C0 * rinv^3
            v2f dens = coef * vexp2(vsplat(NH_L2E) * dist * inv_s2);
            alpha[k] = pi[k] * dens;
            rho[k] = alpha[k] * dens;
        }

        // ---- pi MLP (10 -> 5 -> 5) + softmax over K ----
        v2f piN[Kk];
        {
            v2f h[Kk];
#pragma unroll
            for (int j = 0; j < Kk; j++) {
                const float* row = W + OPW1 + j * 12;
                v2f a = vsplat(W[OPB1 + j]);
                dotseg<5>(a, row + 0, pi);
                dotseg<5>(a, row + 6, alpha);
                h[j] = vrelu(a);
            }
            v2f o[Kk];
            v2f m = vsplat(-1e30f);
#pragma unroll
            for (int j = 0; j < Kk; j++) {
                v2f a = vsplat(W[OPB2 + j]);
                dotseg<5>(a, W + OPW2 + j * 6, h);
                o[j] = a; m = vmax(m, a);
            }
            v2f sum = vsplat(0.0f);
#pragma unroll
            for (int j = 0; j < Kk; j++) { o[j] = vexp2(vsplat(LOG2E) * (o[j] - m)); sum = sum + o[j]; }
            v2f r = vrcp(sum);
#pragma unroll
            for (int j = 0; j < Kk; j++) piN[j] = o[j] * r;
        }

        // ---- mu MLP (23 -> 15 -> 15), sigmoid ----
        v2f muN[CKc];
        {
            v2f h[CKc];
#pragma unroll
            for (int j = 0; j < CKc; j++) {
                const float* row = W + OMW1 + j * 24;
                v2f a = vsplat(W[OMB1 + j]);
                dotseg<3>(a, row + 0, x);
                dotseg<15>(a, row + 4, mu);
                dotseg<5>(a, row + 20, rho);
                h[j] = vrelu(a);
            }
#pragma unroll
            for (int j = 0; j < CKc; j++) {
                v2f a = vsplat(W[OMB2 + j]);
                dotseg<15>(a, W + OMW2 + j * 16, h);
                muN[j] = vsigm(a);
            }
        }

        // ---- sigma MLP (23 -> 5 -> 5): rinvN = exp(-relu(a)) = 1/sigma_new ----
        v2f rinvN[Kk];
        {
            v2f h[Kk];
#pragma unroll
            for (int j = 0; j < Kk; j++) {
                const float* row = W + OSW1 + j * 24;
                v2f a = vsplat(W[OSB1 + j]);
                dotseg<3>(a, row + 0, x);
                dotseg<15>(a, row + 4, muN);
                dotseg<5>(a, row + 20, rho);
                h[j] = vrelu(a);
            }
#pragma unroll
            for (int j = 0; j < Kk; j++) {
                v2f a = vsplat(W[OSB2 + j]);
                dotseg<5>(a, W + OSW2 + j * 6, h);
                rinvN[j] = vexp2(vsplat(-LOG2E) * vrelu(a));
            }
        }

        // ---- dens2(x; muN, 1/rinvN), gamma MLP (5 -> 5 -> 1), sigmoid ----
        v2f gin[Kk];
#pragma unroll
        for (int k = 0; k < Kk; k++) {
            v2f inv_s2 = rinvN[k] * rinvN[k];
            v2f d0 = x[0] - muN[k * Cc + 0];
            v2f d1 = x[1] - muN[k * Cc + 1];
            v2f d2 = x[2] - muN[k * Cc + 2];
            v2f dist = vfma(d0, d0, vfma(d1, d1, d2 * d2));
            v2f coef = vsplat(C0) * inv_s2 * rinvN[k];
            gin[k] = piN[k] * (coef * vexp2(vsplat(NH_L2E) * dist * inv_s2));
        }
        {
            v2f h[Kk];
#pragma unroll
            for (int j = 0; j < Kk; j++) {
                v2f a = vsplat(W[OGB1 + j]);
                dotseg<5>(a, W + OGW1 + j * 6, gin);
                h[j] = vrelu(a);
            }
            v2f go = vsplat(W[OGB2]);
            dotseg<5>(go, W + OGW2, h);
            reinterpret_cast<v2f*>(out + (size_t)(b * Ss + s) * HWc)[rem] = vsigm(go);
        }

        // ---- carry state ----
#pragma unroll
        for (int k = 0; k < Kk; k++) { pi[k] = piN[k]; rinv[k] = rinvN[k]; }
#pragma unroll
        for (int j = 0; j < CKc; j++) mu[j] = muN[j];
#pragma unroll
        for (int c = 0; c < Cc; c++) x[c] = xn[c];
    }
}

} // namespace

extern "C" void kernel_launch(void* const* d_in, const int* in_sizes, int n_in,
                              void* d_out, int out_size, void* d_ws, size_t ws_size,
                              hipStream_t stream) {
    const float* frames = (const float*)d_in[0];
    const float* mu0    = (const float*)d_in[2];
    const float* pw1 = (const float*)d_in[3];
    const float* pb1 = (const float*)d_in[4];
    const float* pw2 = (const float*)d_in[5];
    const float* pb2 = (const float*)d_in[6];
    const float* mw1 = (const float*)d_in[7];
    const float* mb1 = (const float*)d_in[8];
    const float* mw2 = (const float*)d_in[9];
    const float* mb2 = (const float*)d_in[10];
    const float* sw1 = (const float*)d_in[11];
    const float* sb1 = (const float*)d_in[12];
    const float* sw2 = (const float*)d_in[13];
    const float* sb2 = (const float*)d_in[14];
    const float* gw1 = (const float*)d_in[15];
    const float* gb1 = (const float*)d_in[16];
    const float* gw2 = (const float*)d_in[17];
    const float* gb2 = (const float*)d_in[18];
    float* out = (float*)d_out;
    float* ws  = (float*)d_ws;

    // Stage all weights contiguous+padded in d_ws (consumption order).
    stage_ws_kernel<<<1, 256, 0, stream>>>(
        pw1, pb1, pw2, pb2, mw1, mb1, mw2, mb2,
        sw1, sb1, sw2, sb2, gw1, gb1, gw2, gb2, ws);

    const int total2 = Bb * HW2;                     // 294,912 pixel-pairs
    const int grid = (total2 + BLOCK - 1) / BLOCK;   // 2304 blocks of 128

    gmm_seq_kernel<<<grid, BLOCK, 0, stream>>>(frames, mu0, ws, out);
}

// Round 10
// 279.928 us; speedup vs baseline: 1.0286x; 1.0286x over previous
//
#include <hip/hip_runtime.h>

// GMMNet: B=4,S=8,C=3,H=W=384,K=5. Pointwise per pixel; scan over S carries
// per-pixel state (pi[5], mu[15], q[5]=c/sigma) in registers.
//
// Round 10: R8 base (131.4 us; R9's forced 8B s_loads regressed -> reverted).
// Model revision: v_pk_fma_f32 is 4 cyc/wave (157 TF spec cap) -> R8 is
// VALU-execution-bound (model 5340 vs 5800 measured busy cyc/step). This
// round is an instruction diet:
//  (a) layer-2 weights feeding sigmoid/softmax/exp pre-scaled by log2e at
//      staging -> all x LOG2E muls vanish (~26 pk/step)
//  (b) softmax max-subtraction dropped (args provably bounded, exp2 safe)
//  (c) carried state q = c/sigma, c=sqrt(0.5*log2e): density exp2 arg is
//      -dist*q^2 directly (neg folds into modifier)
//  (d) 23-wide dot rows split into 2 accumulators (chain 23 -> 12)
// Weights stay on the scalar/SMEM path, contiguous in d_ws, with the opaque
// per-step scalar offset blocking value-hoisting (R2: 188 VGPR; R3: spill).

namespace {

constexpr int Kk = 5;
constexpr int Cc = 3;
constexpr int CKc = 15;   // C*K
constexpr int Bb = 4;
constexpr int Ss = 8;
constexpr int HWc = 384 * 384;
constexpr int HW2 = HWc / 2;          // pixel-pairs per image
constexpr int BLOCK = 128;

// Contiguous weight layout (float offsets), consumption order (R8 layout).
constexpr int OPB1 = 0;     // pi_b1   5
constexpr int OPW1 = 5;     // pi_w1   5x10 = 50
constexpr int OPB2 = 55;    // pi_b2   5        (xL2E)
constexpr int OPW2 = 60;    // pi_w2   5x5  = 25 (xL2E)
constexpr int OMB1 = 85;    // mu_b1   15
constexpr int OMW1 = 100;   // mu_w1   15x23 = 345
constexpr int OMB2 = 445;   // mu_b2   15       (xL2E)
constexpr int OMW2 = 460;   // mu_w2   15x15 = 225 (xL2E)
constexpr int OSB1 = 685;   // sg_b1   5
constexpr int OSW1 = 690;   // sg_w1   5x23 = 115
constexpr int OSB2 = 805;   // sg_b2   5        (xL2E)
constexpr int OSW2 = 810;   // sg_w2   5x5  = 25 (xL2E)
constexpr int OGB1 = 835;   // ga_b1   5
constexpr int OGW1 = 840;   // ga_w1   5x5  = 25
constexpr int OGW2 = 865;   // ga_w2   5        (xL2E)
constexpr int OGB2 = 870;   // ga_b2   1        (xL2E)
constexpr int WTOT = 871;   // 3484 B

constexpr float LOG2E = 1.4426950408889634f;
constexpr float CQ    = 0.8493218f;      // sqrt(0.5*log2e)
constexpr float C0Q   = 0.10362790f;     // (2pi)^{-3/2} / CQ^3

typedef float v2f __attribute__((ext_vector_type(2)));

__device__ __forceinline__ float rcpf(float x) { return __builtin_amdgcn_rcpf(x); }
__device__ __forceinline__ float ex2(float x) { return __builtin_amdgcn_exp2f(x); }

__device__ __forceinline__ v2f vsplat(float w) { v2f r = {w, w}; return r; }
__device__ __forceinline__ v2f vfma(v2f a, v2f b, v2f c) { return __builtin_elementwise_fma(a, b, c); }
__device__ __forceinline__ v2f wfma(float w, v2f x, v2f c) { return vfma(vsplat(w), x, c); }
__device__ __forceinline__ v2f vexp2(v2f v) { v2f r; r.x = ex2(v.x); r.y = ex2(v.y); return r; }
__device__ __forceinline__ v2f vexp2n(v2f v) { v2f r; r.x = ex2(-v.x); r.y = ex2(-v.y); return r; }
__device__ __forceinline__ v2f vrcp(v2f v) { v2f r; r.x = rcpf(v.x); r.y = rcpf(v.y); return r; }
__device__ __forceinline__ v2f vmax(v2f a, v2f b) { return __builtin_elementwise_max(a, b); }
__device__ __forceinline__ v2f vrelu(v2f a) { return vmax(a, vsplat(0.0f)); }
// sigmoid on a PRE-SCALED (xL2E) argument
__device__ __forceinline__ v2f vsigmP(v2f a) { return vrcp(vsplat(1.0f) + vexp2n(a)); }

__global__ __launch_bounds__(256) void stage_ws_kernel(
    const float* __restrict__ pw1, const float* __restrict__ pb1,
    const float* __restrict__ pw2, const float* __restrict__ pb2,
    const float* __restrict__ mw1, const float* __restrict__ mb1,
    const float* __restrict__ mw2, const float* __restrict__ mb2,
    const float* __restrict__ sw1, const float* __restrict__ sb1,
    const float* __restrict__ sw2, const float* __restrict__ sb2,
    const float* __restrict__ gw1, const float* __restrict__ gb1,
    const float* __restrict__ gw2, const float* __restrict__ gb2,
    float* __restrict__ ws)
{
    const int t = threadIdx.x;
    auto cp = [&](const float* src, int off, int n, float scale) {
        for (int i = t; i < n; i += 256) ws[off + i] = src[i] * scale;
    };
    cp(pb1, OPB1, 5, 1.0f);     cp(pw1, OPW1, 50, 1.0f);
    cp(pb2, OPB2, 5, LOG2E);    cp(pw2, OPW2, 25, LOG2E);
    cp(mb1, OMB1, 15, 1.0f);    cp(mw1, OMW1, 345, 1.0f);
    cp(mb2, OMB2, 15, LOG2E);   cp(mw2, OMW2, 225, LOG2E);
    cp(sb1, OSB1, 5, 1.0f);     cp(sw1, OSW1, 115, 1.0f);
    cp(sb2, OSB2, 5, LOG2E);    cp(sw2, OSW2, 25, LOG2E);
    cp(gb1, OGB1, 5, 1.0f);     cp(gw1, OGW1, 25, 1.0f);
    cp(gw2, OGW2, 5, LOG2E);    cp(gb2, OGB2, 1, LOG2E);
}

__global__ __launch_bounds__(BLOCK) void gmm_seq_kernel(
    const float* __restrict__ frames,
    const float* __restrict__ mu0,
    const float* __restrict__ Wt,     // contiguous weights in d_ws
    float* __restrict__ out)
{
    const int t2 = blockIdx.x * BLOCK + threadIdx.x;   // one thread = 2 adjacent px
    const int b   = t2 / HW2;
    const int rem = t2 - b * HW2;

    // Per-pixel-pair carried state.
    v2f pi[Kk], mu[CKc], q[Kk];                 // q = CQ / sigma
#pragma unroll
    for (int k = 0; k < Kk; k++) { pi[k] = vsplat(0.2f); q[k] = vsplat(CQ); }
    {
        const float* mp = mu0 + (size_t)b * CKc * HWc;
#pragma unroll
        for (int j = 0; j < CKc; j++)
            mu[j] = reinterpret_cast<const v2f*>(mp + (size_t)j * HWc)[rem];
    }

    const float* fbase = frames + ((size_t)b * Ss * Cc) * HWc;
    v2f x[Cc];
#pragma unroll
    for (int c = 0; c < Cc; c++)
        x[c] = reinterpret_cast<const v2f*>(fbase + (size_t)c * HWc)[rem];

#pragma unroll 1
    for (int s = 0; s < Ss; s++) {
        // Opaque per-iteration SCALAR offset: value is always 0 but unprovable.
        // Addresses stay wave-uniform (s_load path), loads stay loop-variant.
        long woff = 0;
        asm volatile("" : "+s"(woff));
        const float* W = Wt + woff;

        // Prefetch next frame's pixels (clamped index -> branchless).
        const int sn = (s + 1 < Ss) ? s + 1 : s;
        v2f xn[Cc];
        {
            const float* fp = fbase + ((size_t)sn * Cc) * HWc;
#pragma unroll
            for (int c = 0; c < Cc; c++)
                xn[c] = reinterpret_cast<const v2f*>(fp + (size_t)c * HWc)[rem];
        }

        // ---- density(x; mu, q): dens = C0Q * q^3 * exp2(-dist*q^2) ----
        v2f alpha[Kk], rho[Kk];
#pragma unroll
        for (int k = 0; k < Kk; k++) {
            v2f q2 = q[k] * q[k];
            v2f d0 = x[0] - mu[k * Cc + 0];
            v2f d1 = x[1] - mu[k * Cc + 1];
            v2f d2 = x[2] - mu[k * Cc + 2];
            v2f dist = vfma(d0, d0, vfma(d1, d1, d2 * d2));
            v2f e = vexp2n(dist * q2);                 // neg folds into modifier
            v2f q3 = q2 * q[k];
            v2f dens = vsplat(C0Q) * (q3 * e);
            alpha[k] = pi[k] * dens;
            rho[k] = alpha[k] * dens;
        }

        // ---- pi MLP (10 -> 5 -> 5) + softmax (no max-subtract; args bounded) ----
        v2f piN[Kk];
        {
            v2f h[Kk];
#pragma unroll
            for (int j = 0; j < Kk; j++) {
                v2f a = vsplat(W[OPB1 + j]);
#pragma unroll
                for (int i = 0; i < Kk; i++) a = wfma(W[OPW1 + j * 2 * Kk + i], pi[i], a);
#pragma unroll
                for (int i = 0; i < Kk; i++) a = wfma(W[OPW1 + j * 2 * Kk + Kk + i], alpha[i], a);
                h[j] = vrelu(a);
            }
            v2f o[Kk], sum = vsplat(0.0f);
#pragma unroll
            for (int j = 0; j < Kk; j++) {
                v2f a = vsplat(W[OPB2 + j]);          // already xL2E
#pragma unroll
                for (int i = 0; i < Kk; i++) a = wfma(W[OPW2 + j * Kk + i], h[i], a);
                o[j] = vexp2(a); sum = sum + o[j];
            }
            v2f r = vrcp(sum);
#pragma unroll
            for (int j = 0; j < Kk; j++) piN[j] = o[j] * r;
        }

        // ---- mu MLP (23 -> 15 -> 15), sigmoid; L1 rows split into 2 chains ----
        v2f muN[CKc];
        {
            v2f h[CKc];
#pragma unroll
            for (int j = 0; j < CKc; j++) {
                const float* row = W + OMW1 + j * 23;
                v2f a0 = vsplat(W[OMB1 + j]);
#pragma unroll
                for (int i = 0; i < Cc; i++) a0 = wfma(row[i], x[i], a0);
#pragma unroll
                for (int i = 0; i < 8; i++)  a0 = wfma(row[3 + i], mu[i], a0);
                v2f a1 = vsplat(row[11]) * mu[8];
#pragma unroll
                for (int i = 9; i < CKc; i++) a1 = wfma(row[3 + i], mu[i], a1);
#pragma unroll
                for (int i = 0; i < Kk; i++)  a1 = wfma(row[18 + i], rho[i], a1);
                h[j] = vrelu(a0 + a1);
            }
#pragma unroll
            for (int j = 0; j < CKc; j++) {
                v2f a = vsplat(W[OMB2 + j]);          // already xL2E
#pragma unroll
                for (int i = 0; i < CKc; i++) a = wfma(W[OMW2 + j * CKc + i], h[i], a);
                muN[j] = vsigmP(a);
            }
        }

        // ---- sigma MLP (23 -> 5 -> 5): qN = CQ * exp2(-relu(a')) ----
        v2f qN[Kk];
        {
            v2f h[Kk];
#pragma unroll
            for (int j = 0; j < Kk; j++) {
                const float* row = W + OSW1 + j * 23;
                v2f a0 = vsplat(W[OSB1 + j]);
#pragma unroll
                for (int i = 0; i < Cc; i++) a0 = wfma(row[i], x[i], a0);
#pragma unroll
                for (int i = 0; i < 8; i++)  a0 = wfma(row[3 + i], muN[i], a0);
                v2f a1 = vsplat(row[11]) * muN[8];
#pragma unroll
                for (int i = 9; i < CKc; i++) a1 = wfma(row[3 + i], muN[i], a1);
#pragma unroll
                for (int i = 0; i < Kk; i++)  a1 = wfma(row[18 + i], rho[i], a1);
                h[j] = vrelu(a0 + a1);
            }
#pragma unroll
            for (int j = 0; j < Kk; j++) {
                v2f a = vsplat(W[OSB2 + j]);          // already xL2E
#pragma unroll
                for (int i = 0; i < Kk; i++) a = wfma(W[OSW2 + j * Kk + i], h[i], a);
                qN[j] = vsplat(CQ) * vexp2n(vrelu(a));
            }
        }

        // ---- dens2(x; muN, qN), gamma MLP (5 -> 5 -> 1), sigmoid ----
        v2f gin[Kk];
#pragma unroll
        for (int k = 0; k < Kk; k++) {
            v2f q2 = qN[k] * qN[k];
            v2f d0 = x[0] - muN[k * Cc + 0];
            v2f d1 = x[1] - muN[k * Cc + 1];
            v2f d2 = x[2] - muN[k * Cc + 2];
            v2f dist = vfma(d0, d0, vfma(d1, d1, d2 * d2));
            v2f e = vexp2n(dist * q2);
            v2f q3 = q2 * qN[k];
            gin[k] = piN[k] * (vsplat(C0Q) * (q3 * e));
        }
        {
            v2f h[Kk];
#pragma unroll
            for (int j = 0; j < Kk; j++) {
                v2f a = vsplat(W[OGB1 + j]);
#pragma unroll
                for (int i = 0; i < Kk; i++) a = wfma(W[OGW1 + j * Kk + i], gin[i], a);
                h[j] = vrelu(a);
            }
            v2f go = vsplat(W[OGB2]);                 // already xL2E
#pragma unroll
            for (int i = 0; i < Kk; i++) go = wfma(W[OGW2 + i], h[i], go);
            reinterpret_cast<v2f*>(out + (size_t)(b * Ss + s) * HWc)[rem] = vsigmP(go);
        }

        // ---- carry state ----
#pragma unroll
        for (int k = 0; k < Kk; k++) { pi[k] = piN[k]; q[k] = qN[k]; }
#pragma unroll
        for (int j = 0; j < CKc; j++) mu[j] = muN[j];
#pragma unroll
        for (int c = 0; c < Cc; c++) x[c] = xn[c];
    }
}

} // namespace

extern "C" void kernel_launch(void* const* d_in, const int* in_sizes, int n_in,
                              void* d_out, int out_size, void* d_ws, size_t ws_size,
                              hipStream_t stream) {
    const float* frames = (const float*)d_in[0];
    const float* mu0    = (const float*)d_in[2];
    const float* pw1 = (const float*)d_in[3];
    const float* pb1 = (const float*)d_in[4];
    const float* pw2 = (const float*)d_in[5];
    const float* pb2 = (const float*)d_in[6];
    const float* mw1 = (const float*)d_in[7];
    const float* mb1 = (const float*)d_in[8];
    const float* mw2 = (const float*)d_in[9];
    const float* mb2 = (const float*)d_in[10];
    const float* sw1 = (const float*)d_in[11];
    const float* sb1 = (const float*)d_in[12];
    const float* sw2 = (const float*)d_in[13];
    const float* sb2 = (const float*)d_in[14];
    const float* gw1 = (const float*)d_in[15];
    const float* gb1 = (const float*)d_in[16];
    const float* gw2 = (const float*)d_in[17];
    const float* gb2 = (const float*)d_in[18];
    float* out = (float*)d_out;
    float* ws  = (float*)d_ws;

    // Stage all weights contiguous in d_ws (consumption order, L2E pre-scaled).
    stage_ws_kernel<<<1, 256, 0, stream>>>(
        pw1, pb1, pw2, pb2, mw1, mb1, mw2, mb2,
        sw1, sb1, sw2, sb2, gw1, gb1, gw2, gb2, ws);

    const int total2 = Bb * HW2;                     // 294,912 pixel-pairs
    const int grid = (total2 + BLOCK - 1) / BLOCK;   // 2304 blocks of 128

    gmm_seq_kernel<<<grid, BLOCK, 0, stream>>>(frames, mu0, ws, out);
}